// Round 3
// baseline (366.833 us; speedup 1.0000x reference)
//
#include <hip/hip_runtime.h>
#include <hip/hip_bf16.h>
#include <math.h>

#define B_  2
#define T_  1024
#define D_  2048
#define H_  16
#define DH_ 128
#define M_  2048          // B_*T_
#define DR_ 1024          // D_/2

typedef __attribute__((ext_vector_type(8))) short short8;
typedef __attribute__((ext_vector_type(4))) short sh4;
typedef __attribute__((ext_vector_type(4))) float f32x4;

// async global->LDS, 16B per lane, dest = wave-uniform base + lane*16
__device__ __forceinline__ void gld16(const __hip_bfloat16* g, __hip_bfloat16* l) {
  __builtin_amdgcn_global_load_lds(
      (const __attribute__((address_space(1))) unsigned int*)g,
      (__attribute__((address_space(3))) unsigned int*)l, 16, 0, 0);
}

#define WAITV(n) asm volatile("s_waitcnt vmcnt(" #n ")" ::: "memory")

// ---------------------------------------------------------------------------
// bf16 MFMA GEMM: C = act(A * B^T + bias). A:[M,K] bf16 rm, B:[N,K] bf16 rm.
// BM x 128 tile, BK=32, FOUR LDS buffers, 3-deep pipeline with COUNTED
// vmcnt (T4, m218): per iter {waitcnt vmcnt(2*LPS); s_barrier; issue
// stage(t+3); 16 MFMA}. vmcnt never drains to 0 in the main loop (tail
// peeled: vmcnt(LPS) then vmcnt(0) so the last tiles are guaranteed
// landed).  256 threads = 4 waves in 2x2.
// Hazards: stage(t+3) overwrites buf (t-1)%4 whose readers (compute(t-1))
// finished before barrier(t); stage(t) landed because only the 2 newest
// stages may remain outstanding (FIFO vmcnt retirement, m135).
// CMODE 0: C fp32 [M,N].
// CMODE 1: Cb bf16 [M,N] only.
// CMODE 4: merged KV. col<2048: C fp32 heads + Cb bf16 heads (k).
//          col>=2048: C2 fp32 heads + Cb2 bf16 transposed [b,h,dh,t] (v).
// ---------------------------------------------------------------------------
template<int BM, int CMODE, bool SILU>
__global__ __launch_bounds__(256)
void gemm_mfma(const __hip_bfloat16* __restrict__ A,
               const __hip_bfloat16* __restrict__ Bm,
               const float* __restrict__ bias,
               float* __restrict__ C, __hip_bfloat16* __restrict__ Cb,
               float* __restrict__ C2, __hip_bfloat16* __restrict__ Cb2,
               int M, int N, int K)
{
  constexpr int NI = BM / 32;           // A-fragment rows per wave (4 or 2)
  constexpr int AC = BM / 64;           // A gld16 calls per wave per stage
  __shared__ __hip_bfloat16 As[4][BM * 32];
  __shared__ __hip_bfloat16 Bs[4][128 * 32];
  const int tid  = threadIdx.x;
  const int wave = tid >> 6;
  const int lane = tid & 63;
  const int m0 = blockIdx.y * BM;
  const int n0 = blockIdx.x * 128;
  const int wm = (wave >> 1) * (BM / 2);   // wave's row half
  const int wn = (wave & 1) * 64;          // wave's col half

  const int srow = lane >> 2;              // 0..15 row within 16-row group
  const int scol = (lane & 3) * 8;         // bf16 element offset in k
  const __hip_bfloat16* Ag = A  + (size_t)(m0 + wave * (BM / 4) + srow) * K + scol;
  const __hip_bfloat16* Bg = Bm + (size_t)(n0 + wave * 32 + srow) * K + scol;

  const int fr = lane & 15;                // fragment row (m/n index)
  const int fk = (lane >> 4) * 8;          // fragment k offset

  f32x4 acc[NI][4];
  #pragma unroll
  for (int i = 0; i < NI; ++i)
    #pragma unroll
    for (int j = 0; j < 4; ++j) acc[i][j] = (f32x4)0.f;

  // stage one BK=32 tile into buffer bf (LPS = AC+2 gld16 per wave)
  auto stage = [&](int bf, int k0) {
    #pragma unroll
    for (int c = 0; c < AC; ++c)
      gld16(Ag + k0 + (size_t)(c * 16) * K,
            &As[bf][(wave * (BM / 4) + c * 16) * 32]);
    #pragma unroll
    for (int c = 0; c < 2; ++c)
      gld16(Bg + k0 + (size_t)(c * 16) * K,
            &Bs[bf][(wave * 32 + c * 16) * 32]);
  };

  const int NT = K >> 5;                   // 64 for K=2048
  stage(0, 0);
  stage(1, 32);
  stage(2, 64);
  int bufc = 0;
  for (int t = 0; t < NT; ++t) {
    // counted wait: allow the 2 newest stages to stay in flight (steady
    // state); tail iterations have fewer younger stages -> tighter counts.
    if constexpr (BM == 128) {
      if (t <= NT - 3)      WAITV(8);
      else if (t == NT - 2) WAITV(4);
      else                  WAITV(0);
    } else {
      if (t <= NT - 3)      WAITV(6);
      else if (t == NT - 2) WAITV(3);
      else                  WAITV(0);
    }
    __builtin_amdgcn_s_barrier();
    if (t + 3 < NT) {
      int b3 = bufc + 3; if (b3 >= 4) b3 -= 4;
      stage(b3, (t + 3) * 32);
    }
    short8 af[NI], bfr[4];
    #pragma unroll
    for (int i = 0; i < NI; ++i)
      af[i]  = *(const short8*)&As[bufc][(wm + i * 16 + fr) * 32 + fk];
    #pragma unroll
    for (int j = 0; j < 4; ++j)
      bfr[j] = *(const short8*)&Bs[bufc][(wn + j * 16 + fr) * 32 + fk];
    __builtin_amdgcn_s_setprio(1);
    #pragma unroll
    for (int i = 0; i < NI; ++i)
      #pragma unroll
      for (int j = 0; j < 4; ++j)
        acc[i][j] = __builtin_amdgcn_mfma_f32_16x16x32_bf16(af[i], bfr[j], acc[i][j], 0, 0, 0);
    __builtin_amdgcn_s_setprio(0);
    bufc = (bufc == 3) ? 0 : bufc + 1;
  }

  // C/D layout (m89-verified): col = lane&15, row = (lane>>4)*4 + reg
  #pragma unroll
  for (int i = 0; i < NI; ++i) {
    #pragma unroll
    for (int j = 0; j < 4; ++j) {
      const int row0 = m0 + wm + i * 16 + (lane >> 4) * 4;
      const int col  = n0 + wn + j * 16 + (lane & 15);
      float vr[4];
      #pragma unroll
      for (int r = 0; r < 4; ++r) {
        float v = acc[i][j][r];
        if (bias) v += bias[col];
        if (SILU) v = v / (1.f + __expf(-v));
        vr[r] = v;
      }
      if (CMODE == 0) {
        #pragma unroll
        for (int r = 0; r < 4; ++r) C[(size_t)(row0 + r) * N + col] = vr[r];
      } else if (CMODE == 1) {
        #pragma unroll
        for (int r = 0; r < 4; ++r) Cb[(size_t)(row0 + r) * N + col] = __float2bfloat16(vr[r]);
      } else {  // CMODE 4
        const int bb = row0 >> 10, t0v = row0 & 1023;   // row = b*T + t
        if (col < D_) {                                  // K head
          const int hh = col >> 7, dd = col & 127;
          #pragma unroll
          for (int r = 0; r < 4; ++r) {
            const size_t idx = (((size_t)(bb * H_ + hh)) * T_ + t0v + r) * DH_ + dd;
            C[idx] = vr[r];
            Cb[idx] = __float2bfloat16(vr[r]);
          }
        } else {                                         // V head (+ transposed bf16)
          const int c2 = col - D_;
          const int hh = c2 >> 7, dd = c2 & 127;
          #pragma unroll
          for (int r = 0; r < 4; ++r)
            C2[(((size_t)(bb * H_ + hh)) * T_ + t0v + r) * DH_ + dd] = vr[r];
          __hip_bfloat16 tmp[4];
          #pragma unroll
          for (int r = 0; r < 4; ++r) tmp[r] = __float2bfloat16(vr[r]);
          *(sh4*)(Cb2 + (((size_t)(bb * H_ + hh)) * DH_ + dd) * T_ + t0v) = *(const sh4*)tmp;
        }
      }
    }
  }
}

// ---------------------------------------------------------------------------
// fp32 -> bf16 conversions for x, wq, wk, wv, wo, rw1 in one launch.
// ---------------------------------------------------------------------------
__global__ __launch_bounds__(256)
void cvt6(const float* __restrict__ s0, const float* __restrict__ s1,
          const float* __restrict__ s2, const float* __restrict__ s3,
          const float* __restrict__ s4, const float* __restrict__ s5,
          __hip_bfloat16* d0, __hip_bfloat16* d1, __hip_bfloat16* d2,
          __hip_bfloat16* d3, __hip_bfloat16* d4, __hip_bfloat16* d5,
          int n0, int n1, int n2, int n3, int n4, int n5)
{
  const float* s; __hip_bfloat16* d; int n;
  switch (blockIdx.y) {
    case 0: s = s0; d = d0; n = n0; break;
    case 1: s = s1; d = d1; n = n1; break;
    case 2: s = s2; d = d2; n = n2; break;
    case 3: s = s3; d = d3; n = n3; break;
    case 4: s = s4; d = d4; n = n4; break;
    default: s = s5; d = d5; n = n5; break;
  }
  const int i = (blockIdx.x * 256 + threadIdx.x) * 4;
  if (i < n) {
    float4 v = *(const float4*)(s + i);
    d[i + 0] = __float2bfloat16(v.x);
    d[i + 1] = __float2bfloat16(v.y);
    d[i + 2] = __float2bfloat16(v.z);
    d[i + 3] = __float2bfloat16(v.w);
  }
}

// ---------------------------------------------------------------------------
// EMA pass 1: local scan per 64-row chunk (carry-in 0). Exact decomposition:
// s_t = local_t + 0.9^(off+1) * carry_chunk, applied later in fuse_bf16.
// ---------------------------------------------------------------------------
__global__ __launch_bounds__(256)
void ema_scan(const float* __restrict__ x, float* __restrict__ l2)
{
  const int b  = blockIdx.z;
  const int t0 = blockIdx.y * 64;
  const int d  = blockIdx.x * 256 + threadIdx.x;
  const float* xp = x  + (size_t)b * T_ * D_ + d;
  float*       lp = l2 + (size_t)b * T_ * D_ + d;
  float s = 0.f;
  #pragma unroll 4
  for (int t = t0; t < t0 + 64; ++t) {
    s = 0.9f * s + 0.1f * xp[(size_t)t * D_];
    lp[(size_t)t * D_] = s;
  }
}

// ---------------------------------------------------------------------------
// EMA pass 2: carry[b,chunk,d] = s at end of previous chunk (global), via
// carry_c = localfinal_{c-1} + 0.9^64 * carry_{c-1};  carry_0 = 0.
// ---------------------------------------------------------------------------
__global__ __launch_bounds__(256)
void ema_carry(const float* __restrict__ l2loc, float* __restrict__ carry)
{
  const int i = blockIdx.x * 256 + threadIdx.x;   // 0..4095
  const int b = i >> 11, d = i & 2047;
  const float A = 1.1790184577738583e-3f;          // 0.9^64
  float c = 0.f;
  carry[((size_t)b * 16 + 0) * D_ + d] = 0.f;
  for (int ch = 1; ch < 16; ++ch) {
    const float lf = l2loc[((size_t)b * T_ + ch * 64 - 1) * D_ + d];
    c = lf + A * c;
    carry[((size_t)b * 16 + ch) * D_ + d] = c;
  }
}

// ---------------------------------------------------------------------------
// Router head: lam = softmax(hdn @ rw2^T + rb2). One wave per row.
// ---------------------------------------------------------------------------
__global__ __launch_bounds__(256)
void router_kernel(const float* __restrict__ hdn, const float* __restrict__ rw2,
                   const float* __restrict__ rb2, float* __restrict__ lam)
{
  const int lane = threadIdx.x & 63;
  const int w    = threadIdx.x >> 6;
  const int m    = blockIdx.x * 4 + w;
  const float* hp = hdn + (size_t)m * DR_;
  float s0 = 0.f, s1 = 0.f, s2 = 0.f;
  for (int k = lane * 4; k < DR_; k += 256) {
    float4 h4 = *(const float4*)(hp + k);
    float4 w0 = *(const float4*)(rw2 + k);
    float4 w1 = *(const float4*)(rw2 + DR_ + k);
    float4 w2 = *(const float4*)(rw2 + 2 * DR_ + k);
    s0 += h4.x * w0.x + h4.y * w0.y + h4.z * w0.z + h4.w * w0.w;
    s1 += h4.x * w1.x + h4.y * w1.y + h4.z * w1.z + h4.w * w1.w;
    s2 += h4.x * w2.x + h4.y * w2.y + h4.z * w2.z + h4.w * w2.w;
  }
  #pragma unroll
  for (int off = 32; off > 0; off >>= 1) {
    s0 += __shfl_down(s0, off);
    s1 += __shfl_down(s1, off);
    s2 += __shfl_down(s2, off);
  }
  if (lane == 0) {
    s0 += rb2[0]; s1 += rb2[1]; s2 += rb2[2];
    float mx = fmaxf(s0, fmaxf(s1, s2));
    float e0 = __expf(s0 - mx), e1 = __expf(s1 - mx), e2 = __expf(s2 - mx);
    float inv = 1.f / (e0 + e1 + e2);
    lam[(size_t)m * 3 + 0] = e0 * inv;
    lam[(size_t)m * 3 + 1] = e1 * inv;
    lam[(size_t)m * 3 + 2] = e2 * inv;
  }
}

// ---------------------------------------------------------------------------
// fused = lam0*x + lam1*(l2local + 0.9^(off+1)*carry) + lam2*l3mem -> bf16
// ---------------------------------------------------------------------------
__global__ __launch_bounds__(256)
void fuse_bf16(const float* __restrict__ x, const float* __restrict__ l2,
               const float* __restrict__ l3m, const float* __restrict__ lam,
               const float* __restrict__ carry, __hip_bfloat16* __restrict__ fb)
{
  const int i4 = blockIdx.x * 256 + threadIdx.x;   // over M_*D_/4
  const int m  = i4 >> 9;                          // D_/4 = 512
  const int c  = (i4 & 511) << 2;
  const int b  = m >> 10;
  const int t  = m & 1023;
  const int ch = t >> 6, off = t & 63;
  const float p = __expf((float)(off + 1) * -0.105360515657f);  // 0.9^(off+1)
  const float w0 = lam[m * 3 + 0], w1 = lam[m * 3 + 1], w2 = lam[m * 3 + 2];
  const float4 xv = *(const float4*)(x   + (size_t)m * D_ + c);
  const float4 ev = *(const float4*)(l2  + (size_t)m * D_ + c);
  const float4 gv = *(const float4*)(l3m + (size_t)b * D_ + c);
  const float4 cv = *(const float4*)(carry + ((size_t)b * 16 + ch) * D_ + c);
  __hip_bfloat16* o = fb + (size_t)m * D_ + c;
  o[0] = __float2bfloat16(w0 * xv.x + w1 * (ev.x + p * cv.x) + w2 * gv.x);
  o[1] = __float2bfloat16(w0 * xv.y + w1 * (ev.y + p * cv.y) + w2 * gv.y);
  o[2] = __float2bfloat16(w0 * xv.z + w1 * (ev.z + p * cv.z) + w2 * gv.z);
  o[3] = __float2bfloat16(w0 * xv.w + w1 * (ev.w + p * cv.w) + w2 * gv.w);
}

// ---------------------------------------------------------------------------
// MFMA flash attention. 64-row Q-tile per block, 4 waves x 16 q-rows,
// 64-key K-tiles, 16x16x32 bf16 MFMA for QK^T and PV.
// qg: bf16 [M,D] row-major; kg: bf16 [b,h,t,dh]; vg: bf16 [b,h,dh,t] (pre-T);
// og: bf16 [b,t,d].
// Grid: 1-D 512 with anti-correlated qt remap: block L and L+256 have
// qt summing to 15 -> co-resident CU pairs carry uniform 17 tile-iters.
// Q fragments loaded global->reg (no Qs LDS): LDS 45KB -> 3 blocks/CU cap.
// Async-STAGE split (T14): next tile's K/V global loads issued before
// compute of current tile; reg->LDS write after the barrier.
// ---------------------------------------------------------------------------
__global__ __launch_bounds__(256)
void flash_mfma(const __hip_bfloat16* __restrict__ qg,
                const __hip_bfloat16* __restrict__ kg,
                const __hip_bfloat16* __restrict__ vg,
                __hip_bfloat16* __restrict__ og)
{
  __shared__ __hip_bfloat16 Ks[64 * 136];
  __shared__ __hip_bfloat16 Vt[128 * 72];
  __shared__ __hip_bfloat16 Ps[64 * 72];
  const int tid  = threadIdx.x;
  const int wave = tid >> 6, lane = tid & 63;
  const int L    = blockIdx.x;
  const int halfg = L >> 8, idx = L & 255;
  const int bh = (idx >> 4) | (halfg << 4);
  const int qt = halfg ? (15 - (idx & 15)) : (idx & 15);
  const int b = bh >> 4, h = bh & 15;
  const int q0 = qt * 64;
  const int lo = lane & 15, hi = lane >> 4;

  // Q fragments directly from global (one-time; rows wave*16+lo, 64B runs)
  short8 aq[4];
  {
    const __hip_bfloat16* qsrc = qg + (size_t)(b * T_ + q0 + wave * 16 + lo) * D_ + h * DH_;
    #pragma unroll
    for (int kk = 0; kk < 4; ++kk)
      aq[kk] = *(const short8*)(qsrc + kk * 32 + hi * 8);
  }

  f32x4 oacc[8];
  #pragma unroll
  for (int i = 0; i < 8; ++i) oacc[i] = (f32x4)0.f;
  float mrow[4] = {-INFINITY, -INFINITY, -INFINITY, -INFINITY};
  float lrow[4] = {0.f, 0.f, 0.f, 0.f};

  const __hip_bfloat16* kbp = kg + (size_t)bh * T_ * DH_;
  const __hip_bfloat16* vbp = vg + (size_t)bh * DH_ * T_;
  const float scale = 0.08838834764831845f;      // 1/sqrt(128)

  // register-staged K/V tile (async split: load early, write late)
  short8 kreg[4], vreg[4];
  auto load_tile = [&](int k0) {
    #pragma unroll
    for (int i = 0; i < 4; ++i) {
      const int ci = tid + 256 * i;
      const int r = ci >> 4, j = ci & 15;
      kreg[i] = *(const short8*)(kbp + (size_t)(k0 + r) * DH_ + j * 8);
      const int dd = ci >> 3, j2 = ci & 7;
      vreg[i] = *(const short8*)(vbp + (size_t)dd * T_ + k0 + j2 * 8);
    }
  };

  load_tile(0);
  for (int kt = 0; kt <= qt; ++kt) {
    // write staged regs -> LDS (compiler inserts vmcnt wait here)
    #pragma unroll
    for (int i = 0; i < 4; ++i) {
      const int ci = tid + 256 * i;
      const int r = ci >> 4, j = ci & 15;
      *(short8*)&Ks[r * 136 + j * 8] = kreg[i];
      const int dd = ci >> 3, j2 = ci & 7;
      *(short8*)&Vt[dd * 72 + j2 * 8] = vreg[i];
    }
    __syncthreads();
    if (kt < qt) load_tile((kt + 1) * 64);   // in flight across compute

    f32x4 sc[4];
    __builtin_amdgcn_s_setprio(1);
    #pragma unroll
    for (int nt = 0; nt < 4; ++nt) {
      sc[nt] = (f32x4)0.f;
      #pragma unroll
      for (int kk = 0; kk < 4; ++kk) {
        short8 bk = *(const short8*)&Ks[(nt * 16 + lo) * 136 + kk * 32 + hi * 8];
        sc[nt] = __builtin_amdgcn_mfma_f32_16x16x32_bf16(aq[kk], bk, sc[nt], 0, 0, 0);
      }
    }
    __builtin_amdgcn_s_setprio(0);
    #pragma unroll
    for (int nt = 0; nt < 4; ++nt)
      #pragma unroll
      for (int r = 0; r < 4; ++r) sc[nt][r] *= scale;
    if (kt == qt) {                           // mask only the diagonal tile
      const int qrow = q0 + wave * 16 + hi * 4;
      #pragma unroll
      for (int nt = 0; nt < 4; ++nt) {
        const int key = qt * 64 + nt * 16 + lo;
        #pragma unroll
        for (int r = 0; r < 4; ++r)
          if (key > qrow + r) sc[nt][r] = -1e30f;
      }
    }
    float alpha[4];
    #pragma unroll
    for (int r = 0; r < 4; ++r) {
      float mx = fmaxf(fmaxf(sc[0][r], sc[1][r]), fmaxf(sc[2][r], sc[3][r]));
      mx = fmaxf(mx, __shfl_xor(mx, 1));
      mx = fmaxf(mx, __shfl_xor(mx, 2));
      mx = fmaxf(mx, __shfl_xor(mx, 4));
      mx = fmaxf(mx, __shfl_xor(mx, 8));
      const float nm = fmaxf(mrow[r], mx);
      alpha[r] = __expf(mrow[r] - nm);
      mrow[r] = nm;
      float ls = 0.f;
      #pragma unroll
      for (int nt = 0; nt < 4; ++nt) {
        float p = __expf(sc[nt][r] - nm);
        sc[nt][r] = p;
        ls += p;
      }
      ls += __shfl_xor(ls, 1);
      ls += __shfl_xor(ls, 2);
      ls += __shfl_xor(ls, 4);
      ls += __shfl_xor(ls, 8);
      lrow[r] = lrow[r] * alpha[r] + ls;
    }
    #pragma unroll
    for (int nt = 0; nt < 4; ++nt)
      #pragma unroll
      for (int r = 0; r < 4; ++r)
        Ps[(wave * 16 + hi * 4 + r) * 72 + nt * 16 + lo] = __float2bfloat16(sc[nt][r]);
    #pragma unroll
    for (int n2 = 0; n2 < 8; ++n2)
      #pragma unroll
      for (int r = 0; r < 4; ++r) oacc[n2][r] *= alpha[r];
    short8 ap[2];
    #pragma unroll
    for (int k2 = 0; k2 < 2; ++k2)
      ap[k2] = *(const short8*)&Ps[(wave * 16 + lo) * 72 + k2 * 32 + hi * 8];
    __builtin_amdgcn_s_setprio(1);
    #pragma unroll
    for (int n2 = 0; n2 < 8; ++n2) {
      #pragma unroll
      for (int k2 = 0; k2 < 2; ++k2) {
        short8 bv = *(const short8*)&Vt[(n2 * 16 + lo) * 72 + k2 * 32 + hi * 8];
        oacc[n2] = __builtin_amdgcn_mfma_f32_16x16x32_bf16(ap[k2], bv, oacc[n2], 0, 0, 0);
      }
    }
    __builtin_amdgcn_s_setprio(0);
    __syncthreads();   // LDS reads done before next iteration's writes
  }

  float inv[4];
  #pragma unroll
  for (int r = 0; r < 4; ++r) inv[r] = 1.f / lrow[r];
  __hip_bfloat16* od = og + (size_t)(b * T_ + q0 + wave * 16 + hi * 4) * D_ + h * DH_;
  #pragma unroll
  for (int n2 = 0; n2 < 8; ++n2)
    #pragma unroll
    for (int r = 0; r < 4; ++r)
      od[(size_t)r * D_ + n2 * 16 + lo] = __float2bfloat16(oacc[n2][r] * inv[r]);
}

// ---------------------------------------------------------------------------
extern "C" void kernel_launch(void* const* d_in, const int* in_sizes, int n_in,
                              void* d_out, int out_size, void* d_ws, size_t ws_size,
                              hipStream_t stream)
{
  const float* x   = (const float*)d_in[0];
  const float* l3m = (const float*)d_in[1];
  const float* wq  = (const float*)d_in[2];
  const float* wk  = (const float*)d_in[3];
  const float* wv  = (const float*)d_in[4];
  const float* wo  = (const float*)d_in[5];
  const float* rw1 = (const float*)d_in[6];
  const float* rb1 = (const float*)d_in[7];
  const float* rw2 = (const float*)d_in[8];
  const float* rb2 = (const float*)d_in[9];

  float* out = (float*)d_out;                 // [b,t,d]      4,194,304 f32
  float* kh  = out + 4194304;                 // [b,h,t,dh]   4,194,304 f32
  float* vh  = out + 8388608;                 // [b,h,t,dh]   4,194,304 f32
  float* lam = out + 12582912;                // [b,t,3]          6,144 f32

  // ws layout (80 MB):
  char* wsb = (char*)d_ws;
  float*          l2_f32 = (float*)(wsb);                        // 16 MB (local scan)
  float*          hdn    = (float*)(wsb + (16u << 20));          //  8 MB
  __hip_bfloat16* wkb    = (__hip_bfloat16*)(wsb + (24u << 20)); //  8 MB \ contiguous
  __hip_bfloat16* wvb    = (__hip_bfloat16*)(wsb + (32u << 20)); //  8 MB / [4096,2048]
  __hip_bfloat16* wob    = (__hip_bfloat16*)(wsb + (40u << 20)); //  8 MB
  __hip_bfloat16* fusedb = (__hip_bfloat16*)(wsb + (48u << 20)); //  8 MB
  __hip_bfloat16* attnb  = (__hip_bfloat16*)(wsb + (56u << 20)); //  8 MB (written step 9)
  __hip_bfloat16* khb    = (__hip_bfloat16*)(wsb + (64u << 20)); //  8 MB bf16 heads
  __hip_bfloat16* vtb    = (__hip_bfloat16*)(wsb + (72u << 20)); //  8 MB bf16 [b,h,dh,t]
  float*          carry  = (float*)attnb;   // 256 KB; dead before attnb written
  // d_out scratch reuse (regions written later in the stream order):
  __hip_bfloat16* wqb  = (__hip_bfloat16*)kh;                    // [16,24 MB) of d_out
  __hip_bfloat16* rw1b = (__hip_bfloat16*)kh + 4194304;          // [24,28 MB)
  __hip_bfloat16* xb   = (__hip_bfloat16*)vh;                    // [32,40 MB)
  __hip_bfloat16* qb   = (__hip_bfloat16*)out;                   // [0,8 MB); out written last

  dim3 blk(256);

  // 1. fp32->bf16: x, wq, wk, wv, wo, rw1
  cvt6<<<dim3(4096, 6), blk, 0, stream>>>(x, wq, wk, wv, wo, rw1,
                                          xb, wqb, wkb, wvb, wob, rw1b,
                                          M_ * D_, D_ * D_, D_ * D_, D_ * D_, D_ * D_, DR_ * D_);
  // 2. EMA pass1: local 64-chunk scans (exact; carry applied in fuse)
  ema_scan<<<dim3(8, 16, 2), blk, 0, stream>>>(x, l2_f32);
  // 3. EMA pass2: cross-chunk carries
  ema_carry<<<dim3(16), blk, 0, stream>>>(l2_f32, carry);
  // 4. qb = bf16(x @ wq^T)   (64x128 tiles -> 512 WGs, 3 blocks/CU)
  gemm_mfma<64, 1, false><<<dim3(16, 32), blk, 0, stream>>>(xb, wqb, nullptr, nullptr, qb, nullptr, nullptr, M_, D_, D_);
  // 5. hdn = silu(q @ rw1^T + rb1)   (64x128 -> 256 WGs, full-chip)
  gemm_mfma<64, 0, true><<<dim3(8, 32), blk, 0, stream>>>(qb, rw1b, rb1, hdn, nullptr, nullptr, nullptr, M_, DR_, D_);
  // 6. lam = softmax(hdn @ rw2^T + rb2)
  router_kernel<<<dim3(512), blk, 0, stream>>>(hdn, rw2, rb2, lam);
  // 7. fused = lam0*x + lam1*l2 + lam2*l3  -> bf16 (applies EMA carry)
  fuse_bf16<<<dim3(4096), blk, 0, stream>>>(x, l2_f32, l3m, lam, carry, fusedb);
  // 8. merged KV GEMM (N=4096): kh fp32+khb bf16 heads; vh fp32+vtb bf16 transposed
  gemm_mfma<128, 4, false><<<dim3(32, 16), blk, 0, stream>>>(fusedb, wkb, nullptr, kh, khb, vh, vtb, M_, 2 * D_, D_);
  // 9. MFMA flash attention -> bf16 attnb [b,t,d]  (balanced 1-D grid)
  flash_mfma<<<dim3(512), blk, 0, stream>>>(qb, khb, vtb, attnb);
  // 10. out = attn @ wo^T   (64x128 -> 512 WGs)
  gemm_mfma<64, 0, false><<<dim3(16, 32), blk, 0, stream>>>(attnb, wob, nullptr, out, nullptr, nullptr, nullptr, M_, D_, D_);
}

// Round 4
// 349.304 us; speedup vs baseline: 1.0502x; 1.0502x over previous
//
#include <hip/hip_runtime.h>
#include <hip/hip_bf16.h>
#include <math.h>

#define B_  2
#define T_  1024
#define D_  2048
#define H_  16
#define DH_ 128
#define M_  2048          // B_*T_
#define DR_ 1024          // D_/2
#define CH_  16           // EMA chunk length
#define NCH_ 64           // chunks per sequence (T_/CH_)

typedef __attribute__((ext_vector_type(8))) short short8;
typedef __attribute__((ext_vector_type(4))) short sh4;
typedef __attribute__((ext_vector_type(4))) float f32x4;

// async global->LDS, 16B per lane, dest = wave-uniform base + lane*16
__device__ __forceinline__ void gld16(const __hip_bfloat16* g, __hip_bfloat16* l) {
  __builtin_amdgcn_global_load_lds(
      (const __attribute__((address_space(1))) unsigned int*)g,
      (__attribute__((address_space(3))) unsigned int*)l, 16, 0, 0);
}

// ---------------------------------------------------------------------------
// bf16 MFMA GEMM: C = act(A * B^T + bias). A:[M,K] bf16 rm, B:[N,K] bf16 rm.
// BM x 128 tile, BK=64 (two 32-col halves), double-buffered LDS, 2-phase
// pipeline: stage(t+1) issued BEFORE compute(t); one __syncthreads per
// K-step (its implicit vmcnt(0) drain is the only wait -> load latency of
// t+1 hides under compute(t)).  256 threads = 4 waves in 2x2.
// (Round-3 counted-vmcnt 4-buffer attempt REGRESSED: T4 needs the full
// 8-wave 256-square 8-phase template, not this 4-wave structure.)
// CMODE 0: C fp32 [M,N].
// CMODE 1: Cb bf16 [M,N] only.
// CMODE 4: merged KV. col<2048: C fp32 heads + Cb bf16 heads (k).
//          col>=2048: C2 fp32 heads + Cb2 bf16 transposed [b,h,dh,t] (v).
// ---------------------------------------------------------------------------
template<int BM, int CMODE, bool SILU>
__global__ __launch_bounds__(256)
void gemm_mfma(const __hip_bfloat16* __restrict__ A,
               const __hip_bfloat16* __restrict__ Bm,
               const float* __restrict__ bias,
               float* __restrict__ C, __hip_bfloat16* __restrict__ Cb,
               float* __restrict__ C2, __hip_bfloat16* __restrict__ Cb2,
               int M, int N, int K)
{
  constexpr int NI = BM / 32;           // A-fragment rows per wave (4 or 2)
  constexpr int AC = BM / 64;           // A gld16 calls per wave per half (2 or 1)
  __shared__ __hip_bfloat16 As[2][2][BM * 32];    // [buf][k-half][BM x 32]
  __shared__ __hip_bfloat16 Bs[2][2][128 * 32];
  const int tid  = threadIdx.x;
  const int wave = tid >> 6;
  const int lane = tid & 63;
  const int m0 = blockIdx.y * BM;
  const int n0 = blockIdx.x * 128;
  const int wm = (wave >> 1) * (BM / 2);   // wave's row half
  const int wn = (wave & 1) * 64;          // wave's col half

  const int srow = lane >> 2;              // 0..15 row within 16-row group
  const int scol = (lane & 3) * 8;         // bf16 element offset in k
  const __hip_bfloat16* Ag = A  + (size_t)(m0 + wave * (BM / 4) + srow) * K + scol;
  const __hip_bfloat16* Bg = Bm + (size_t)(n0 + wave * 32 + srow) * K + scol;

  const int fr = lane & 15;                // fragment row (m/n index)
  const int fk = (lane >> 4) * 8;          // fragment k offset

  f32x4 acc[NI][4];
  #pragma unroll
  for (int i = 0; i < NI; ++i)
    #pragma unroll
    for (int j = 0; j < 4; ++j) acc[i][j] = (f32x4)0.f;

  // stage one BK=64 tile (both 32-col halves) into buffer bf
  auto stage = [&](int bf, int k0) {
    #pragma unroll
    for (int h = 0; h < 2; ++h) {
      #pragma unroll
      for (int c = 0; c < AC; ++c)
        gld16(Ag + k0 + h * 32 + (size_t)(c * 16) * K,
              &As[bf][h][(wave * (BM / 4) + c * 16) * 32]);
      #pragma unroll
      for (int c = 0; c < 2; ++c)
        gld16(Bg + k0 + h * 32 + (size_t)(c * 16) * K,
              &Bs[bf][h][(wave * 32 + c * 16) * 32]);
    }
  };

  stage(0, 0);
  __syncthreads();                         // prologue drain (vmcnt(0))
  int cur = 0;
  for (int k0 = 0; k0 < K; k0 += 64) {
    if (k0 + 64 < K) stage(cur ^ 1, k0 + 64);   // issue next tile FIRST
    #pragma unroll
    for (int h = 0; h < 2; ++h) {
      short8 af[NI], bfr[4];
      #pragma unroll
      for (int i = 0; i < NI; ++i)
        af[i]  = *(const short8*)&As[cur][h][(wm + i * 16 + fr) * 32 + fk];
      #pragma unroll
      for (int j = 0; j < 4; ++j)
        bfr[j] = *(const short8*)&Bs[cur][h][(wn + j * 16 + fr) * 32 + fk];
      #pragma unroll
      for (int i = 0; i < NI; ++i)
        #pragma unroll
        for (int j = 0; j < 4; ++j)
          acc[i][j] = __builtin_amdgcn_mfma_f32_16x16x32_bf16(af[i], bfr[j], acc[i][j], 0, 0, 0);
    }
    __syncthreads();   // vmcnt(0)+lgkmcnt(0) drain: next tile landed, reads done
    cur ^= 1;
  }

  // C/D layout (m89-verified): col = lane&15, row = (lane>>4)*4 + reg
  #pragma unroll
  for (int i = 0; i < NI; ++i) {
    #pragma unroll
    for (int j = 0; j < 4; ++j) {
      const int row0 = m0 + wm + i * 16 + (lane >> 4) * 4;
      const int col  = n0 + wn + j * 16 + (lane & 15);
      float vr[4];
      #pragma unroll
      for (int r = 0; r < 4; ++r) {
        float v = acc[i][j][r];
        if (bias) v += bias[col];
        if (SILU) v = v / (1.f + __expf(-v));
        vr[r] = v;
      }
      if (CMODE == 0) {
        #pragma unroll
        for (int r = 0; r < 4; ++r) C[(size_t)(row0 + r) * N + col] = vr[r];
      } else if (CMODE == 1) {
        #pragma unroll
        for (int r = 0; r < 4; ++r) Cb[(size_t)(row0 + r) * N + col] = __float2bfloat16(vr[r]);
      } else {  // CMODE 4
        const int bb = row0 >> 10, t0v = row0 & 1023;   // row = b*T + t
        if (col < D_) {                                  // K head
          const int hh = col >> 7, dd = col & 127;
          #pragma unroll
          for (int r = 0; r < 4; ++r) {
            const size_t idx = (((size_t)(bb * H_ + hh)) * T_ + t0v + r) * DH_ + dd;
            C[idx] = vr[r];
            Cb[idx] = __float2bfloat16(vr[r]);
          }
        } else {                                         // V head (+ transposed bf16)
          const int c2 = col - D_;
          const int hh = c2 >> 7, dd = c2 & 127;
          #pragma unroll
          for (int r = 0; r < 4; ++r)
            C2[(((size_t)(bb * H_ + hh)) * T_ + t0v + r) * DH_ + dd] = vr[r];
          __hip_bfloat16 tmp[4];
          #pragma unroll
          for (int r = 0; r < 4; ++r) tmp[r] = __float2bfloat16(vr[r]);
          *(sh4*)(Cb2 + (((size_t)(bb * H_ + hh)) * DH_ + dd) * T_ + t0v) = *(const sh4*)tmp;
        }
      }
    }
  }
}

// ---------------------------------------------------------------------------
// prep_scan: single pass over x. Reads x once (float4/lane = 1KB/wave),
// writes xb (bf16, 8B vector store) AND the local EMA scan l2 per 16-row
// chunk (carry-in 0; exact decomposition, carry applied in fuse_bf16).
// Grid (2 dblk, 64 chunks, 2 b) = 256 blocks.
// ---------------------------------------------------------------------------
__global__ __launch_bounds__(256)
void prep_scan(const float* __restrict__ x, __hip_bfloat16* __restrict__ xb,
               float* __restrict__ l2)
{
  const int b  = blockIdx.z;
  const int t0 = blockIdx.y * CH_;
  const int d  = blockIdx.x * 1024 + threadIdx.x * 4;
  const float* xp = x  + (size_t)b * T_ * D_ + d;
  float*       lp = l2 + (size_t)b * T_ * D_ + d;
  __hip_bfloat16* xo = xb + (size_t)b * T_ * D_ + d;
  float4 s = make_float4(0.f, 0.f, 0.f, 0.f);
  #pragma unroll 4
  for (int t = t0; t < t0 + CH_; ++t) {
    float4 v = *(const float4*)(xp + (size_t)t * D_);
    __hip_bfloat16 tmp[4] = {__float2bfloat16(v.x), __float2bfloat16(v.y),
                             __float2bfloat16(v.z), __float2bfloat16(v.w)};
    *(sh4*)(xo + (size_t)t * D_) = *(const sh4*)tmp;
    s.x = 0.9f * s.x + 0.1f * v.x;
    s.y = 0.9f * s.y + 0.1f * v.y;
    s.z = 0.9f * s.z + 0.1f * v.z;
    s.w = 0.9f * s.w + 0.1f * v.w;
    *(float4*)(lp + (size_t)t * D_) = s;
  }
}

// ---------------------------------------------------------------------------
// fp32 -> bf16 conversions for wq, wk, wv, wo, rw1 (16B vector stores).
// ---------------------------------------------------------------------------
__global__ __launch_bounds__(256)
void cvt5(const float* __restrict__ s0, const float* __restrict__ s1,
          const float* __restrict__ s2, const float* __restrict__ s3,
          const float* __restrict__ s4,
          __hip_bfloat16* d0, __hip_bfloat16* d1, __hip_bfloat16* d2,
          __hip_bfloat16* d3, __hip_bfloat16* d4,
          int n0, int n1, int n2, int n3, int n4)
{
  const float* s; __hip_bfloat16* d; int n;
  switch (blockIdx.y) {
    case 0: s = s0; d = d0; n = n0; break;
    case 1: s = s1; d = d1; n = n1; break;
    case 2: s = s2; d = d2; n = n2; break;
    case 3: s = s3; d = d3; n = n3; break;
    default: s = s4; d = d4; n = n4; break;
  }
  const int i = (blockIdx.x * 256 + threadIdx.x) * 8;
  if (i < n) {
    float4 a = *(const float4*)(s + i);
    float4 b = *(const float4*)(s + i + 4);
    __hip_bfloat16 t[8] = {__float2bfloat16(a.x), __float2bfloat16(a.y),
                           __float2bfloat16(a.z), __float2bfloat16(a.w),
                           __float2bfloat16(b.x), __float2bfloat16(b.y),
                           __float2bfloat16(b.z), __float2bfloat16(b.w)};
    *(short8*)(d + i) = *(const short8*)t;
  }
}

// ---------------------------------------------------------------------------
// EMA pass 2: carry[b,chunk,d] = s at end of previous chunk (global), via
// carry_c = localfinal_{c-1} + 0.9^16 * carry_{c-1};  carry_0 = 0.
// 64 chunks of 16. Grid 64 blocks x 64 threads (4096 (b,d) chains).
// ---------------------------------------------------------------------------
__global__ __launch_bounds__(64)
void ema_carry(const float* __restrict__ l2loc, float* __restrict__ carry)
{
  const int i = blockIdx.x * 64 + threadIdx.x;    // 0..4095
  const int b = i >> 11, d = i & 2047;
  const float A = 0.18530201888518416f;            // 0.9^16
  float c = 0.f;
  carry[((size_t)b * NCH_ + 0) * D_ + d] = 0.f;
  for (int ch = 1; ch < NCH_; ++ch) {
    const float lf = l2loc[((size_t)b * T_ + ch * CH_ - 1) * D_ + d];
    c = lf + A * c;
    carry[((size_t)b * NCH_ + ch) * D_ + d] = c;
  }
}

// ---------------------------------------------------------------------------
// Router head: lam = softmax(hdn @ rw2^T + rb2). One wave per row.
// ---------------------------------------------------------------------------
__global__ __launch_bounds__(256)
void router_kernel(const float* __restrict__ hdn, const float* __restrict__ rw2,
                   const float* __restrict__ rb2, float* __restrict__ lam)
{
  const int lane = threadIdx.x & 63;
  const int w    = threadIdx.x >> 6;
  const int m    = blockIdx.x * 4 + w;
  const float* hp = hdn + (size_t)m * DR_;
  float s0 = 0.f, s1 = 0.f, s2 = 0.f;
  for (int k = lane * 4; k < DR_; k += 256) {
    float4 h4 = *(const float4*)(hp + k);
    float4 w0 = *(const float4*)(rw2 + k);
    float4 w1 = *(const float4*)(rw2 + DR_ + k);
    float4 w2 = *(const float4*)(rw2 + 2 * DR_ + k);
    s0 += h4.x * w0.x + h4.y * w0.y + h4.z * w0.z + h4.w * w0.w;
    s1 += h4.x * w1.x + h4.y * w1.y + h4.z * w1.z + h4.w * w1.w;
    s2 += h4.x * w2.x + h4.y * w2.y + h4.z * w2.z + h4.w * w2.w;
  }
  #pragma unroll
  for (int off = 32; off > 0; off >>= 1) {
    s0 += __shfl_down(s0, off);
    s1 += __shfl_down(s1, off);
    s2 += __shfl_down(s2, off);
  }
  if (lane == 0) {
    s0 += rb2[0]; s1 += rb2[1]; s2 += rb2[2];
    float mx = fmaxf(s0, fmaxf(s1, s2));
    float e0 = __expf(s0 - mx), e1 = __expf(s1 - mx), e2 = __expf(s2 - mx);
    float inv = 1.f / (e0 + e1 + e2);
    lam[(size_t)m * 3 + 0] = e0 * inv;
    lam[(size_t)m * 3 + 1] = e1 * inv;
    lam[(size_t)m * 3 + 2] = e2 * inv;
  }
}

// ---------------------------------------------------------------------------
// fused = lam0*x + lam1*(l2local + 0.9^(off+1)*carry) + lam2*l3mem -> bf16
// 8 elems/thread, 16B vector store.
// ---------------------------------------------------------------------------
__global__ __launch_bounds__(256)
void fuse_bf16(const float* __restrict__ x, const float* __restrict__ l2,
               const float* __restrict__ l3m, const float* __restrict__ lam,
               const float* __restrict__ carry, __hip_bfloat16* __restrict__ fb)
{
  const int i8 = blockIdx.x * 256 + threadIdx.x;   // over M_*D_/8
  const int m  = i8 >> 8;                          // D_/8 = 256
  const int c  = (i8 & 255) << 3;
  const int b  = m >> 10;
  const int t  = m & 1023;
  const int ch = t >> 4, off = t & 15;
  const float p = __expf((float)(off + 1) * -0.105360515657f);  // 0.9^(off+1)
  const float w0 = lam[m * 3 + 0], w1 = lam[m * 3 + 1], w2 = lam[m * 3 + 2];
  const float* xp = x   + (size_t)m * D_ + c;
  const float* ep = l2  + (size_t)m * D_ + c;
  const float* gp = l3m + (size_t)b * D_ + c;
  const float* cp = carry + ((size_t)b * NCH_ + ch) * D_ + c;
  __hip_bfloat16 tmp[8];
  #pragma unroll
  for (int q = 0; q < 2; ++q) {
    float4 xv = *(const float4*)(xp + q * 4);
    float4 ev = *(const float4*)(ep + q * 4);
    float4 gv = *(const float4*)(gp + q * 4);
    float4 cv = *(const float4*)(cp + q * 4);
    tmp[q * 4 + 0] = __float2bfloat16(w0 * xv.x + w1 * (ev.x + p * cv.x) + w2 * gv.x);
    tmp[q * 4 + 1] = __float2bfloat16(w0 * xv.y + w1 * (ev.y + p * cv.y) + w2 * gv.y);
    tmp[q * 4 + 2] = __float2bfloat16(w0 * xv.z + w1 * (ev.z + p * cv.z) + w2 * gv.z);
    tmp[q * 4 + 3] = __float2bfloat16(w0 * xv.w + w1 * (ev.w + p * cv.w) + w2 * gv.w);
  }
  *(short8*)(fb + (size_t)m * D_ + c) = *(const short8*)tmp;
}

// ---------------------------------------------------------------------------
// MFMA flash attention. 64-row Q-tile per block, 4 waves x 16 q-rows,
// 64-key K-tiles, 16x16x32 bf16 MFMA for QK^T and PV.
// qg: bf16 [M,D] row-major; kg: bf16 [b,h,t,dh]; vg: bf16 [b,h,dh,t] (pre-T);
// og: bf16 [b,t,d].
// Grid: 1-D 512 with anti-correlated qt remap: block L and L+256 have
// qt summing to 15 -> co-resident CU pairs carry uniform 17 tile-iters.
// Q fragments loaded global->reg (no Qs LDS): LDS 45KB.
// Async-STAGE split (T14): next tile's K/V global loads issued before
// compute of current tile; reg->LDS write after the barrier.
// ---------------------------------------------------------------------------
__global__ __launch_bounds__(256)
void flash_mfma(const __hip_bfloat16* __restrict__ qg,
                const __hip_bfloat16* __restrict__ kg,
                const __hip_bfloat16* __restrict__ vg,
                __hip_bfloat16* __restrict__ og)
{
  __shared__ __hip_bfloat16 Ks[64 * 136];
  __shared__ __hip_bfloat16 Vt[128 * 72];
  __shared__ __hip_bfloat16 Ps[64 * 72];
  const int tid  = threadIdx.x;
  const int wave = tid >> 6, lane = tid & 63;
  const int L    = blockIdx.x;
  const int halfg = L >> 8, idx = L & 255;
  const int bh = (idx >> 4) | (halfg << 4);
  const int qt = halfg ? (15 - (idx & 15)) : (idx & 15);
  const int b = bh >> 4, h = bh & 15;
  const int q0 = qt * 64;
  const int lo = lane & 15, hi = lane >> 4;

  // Q fragments directly from global (one-time; rows wave*16+lo, 64B runs)
  short8 aq[4];
  {
    const __hip_bfloat16* qsrc = qg + (size_t)(b * T_ + q0 + wave * 16 + lo) * D_ + h * DH_;
    #pragma unroll
    for (int kk = 0; kk < 4; ++kk)
      aq[kk] = *(const short8*)(qsrc + kk * 32 + hi * 8);
  }

  f32x4 oacc[8];
  #pragma unroll
  for (int i = 0; i < 8; ++i) oacc[i] = (f32x4)0.f;
  float mrow[4] = {-INFINITY, -INFINITY, -INFINITY, -INFINITY};
  float lrow[4] = {0.f, 0.f, 0.f, 0.f};

  const __hip_bfloat16* kbp = kg + (size_t)bh * T_ * DH_;
  const __hip_bfloat16* vbp = vg + (size_t)bh * DH_ * T_;
  const float scale = 0.08838834764831845f;      // 1/sqrt(128)

  // register-staged K/V tile (async split: load early, write late)
  short8 kreg[4], vreg[4];
  auto load_tile = [&](int k0) {
    #pragma unroll
    for (int i = 0; i < 4; ++i) {
      const int ci = tid + 256 * i;
      const int r = ci >> 4, j = ci & 15;
      kreg[i] = *(const short8*)(kbp + (size_t)(k0 + r) * DH_ + j * 8);
      const int dd = ci >> 3, j2 = ci & 7;
      vreg[i] = *(const short8*)(vbp + (size_t)dd * T_ + k0 + j2 * 8);
    }
  };

  load_tile(0);
  for (int kt = 0; kt <= qt; ++kt) {
    // write staged regs -> LDS (compiler inserts vmcnt wait here)
    #pragma unroll
    for (int i = 0; i < 4; ++i) {
      const int ci = tid + 256 * i;
      const int r = ci >> 4, j = ci & 15;
      *(short8*)&Ks[r * 136 + j * 8] = kreg[i];
      const int dd = ci >> 3, j2 = ci & 7;
      *(short8*)&Vt[dd * 72 + j2 * 8] = vreg[i];
    }
    __syncthreads();
    if (kt < qt) load_tile((kt + 1) * 64);   // in flight across compute

    f32x4 sc[4];
    __builtin_amdgcn_s_setprio(1);
    #pragma unroll
    for (int nt = 0; nt < 4; ++nt) {
      sc[nt] = (f32x4)0.f;
      #pragma unroll
      for (int kk = 0; kk < 4; ++kk) {
        short8 bk = *(const short8*)&Ks[(nt * 16 + lo) * 136 + kk * 32 + hi * 8];
        sc[nt] = __builtin_amdgcn_mfma_f32_16x16x32_bf16(aq[kk], bk, sc[nt], 0, 0, 0);
      }
    }
    __builtin_amdgcn_s_setprio(0);
    #pragma unroll
    for (int nt = 0; nt < 4; ++nt)
      #pragma unroll
      for (int r = 0; r < 4; ++r) sc[nt][r] *= scale;
    if (kt == qt) {                           // mask only the diagonal tile
      const int qrow = q0 + wave * 16 + hi * 4;
      #pragma unroll
      for (int nt = 0; nt < 4; ++nt) {
        const int key = qt * 64 + nt * 16 + lo;
        #pragma unroll
        for (int r = 0; r < 4; ++r)
          if (key > qrow + r) sc[nt][r] = -1e30f;
      }
    }
    float alpha[4];
    #pragma unroll
    for (int r = 0; r < 4; ++r) {
      float mx = fmaxf(fmaxf(sc[0][r], sc[1][r]), fmaxf(sc[2][r], sc[3][r]));
      mx = fmaxf(mx, __shfl_xor(mx, 1));
      mx = fmaxf(mx, __shfl_xor(mx, 2));
      mx = fmaxf(mx, __shfl_xor(mx, 4));
      mx = fmaxf(mx, __shfl_xor(mx, 8));
      const float nm = fmaxf(mrow[r], mx);
      alpha[r] = __expf(mrow[r] - nm);
      mrow[r] = nm;
      float ls = 0.f;
      #pragma unroll
      for (int nt = 0; nt < 4; ++nt) {
        float p = __expf(sc[nt][r] - nm);
        sc[nt][r] = p;
        ls += p;
      }
      ls += __shfl_xor(ls, 1);
      ls += __shfl_xor(ls, 2);
      ls += __shfl_xor(ls, 4);
      ls += __shfl_xor(ls, 8);
      lrow[r] = lrow[r] * alpha[r] + ls;
    }
    #pragma unroll
    for (int nt = 0; nt < 4; ++nt)
      #pragma unroll
      for (int r = 0; r < 4; ++r)
        Ps[(wave * 16 + hi * 4 + r) * 72 + nt * 16 + lo] = __float2bfloat16(sc[nt][r]);
    #pragma unroll
    for (int n2 = 0; n2 < 8; ++n2)
      #pragma unroll
      for (int r = 0; r < 4; ++r) oacc[n2][r] *= alpha[r];
    short8 ap[2];
    #pragma unroll
    for (int k2 = 0; k2 < 2; ++k2)
      ap[k2] = *(const short8*)&Ps[(wave * 16 + lo) * 72 + k2 * 32 + hi * 8];
    __builtin_amdgcn_s_setprio(1);
    #pragma unroll
    for (int n2 = 0; n2 < 8; ++n2) {
      #pragma unroll
      for (int k2 = 0; k2 < 2; ++k2) {
        short8 bv = *(const short8*)&Vt[(n2 * 16 + lo) * 72 + k2 * 32 + hi * 8];
        oacc[n2] = __builtin_amdgcn_mfma_f32_16x16x32_bf16(ap[k2], bv, oacc[n2], 0, 0, 0);
      }
    }
    __builtin_amdgcn_s_setprio(0);
    __syncthreads();   // LDS reads done before next iteration's writes
  }

  float inv[4];
  #pragma unroll
  for (int r = 0; r < 4; ++r) inv[r] = 1.f / lrow[r];
  __hip_bfloat16* od = og + (size_t)(b * T_ + q0 + wave * 16 + hi * 4) * D_ + h * DH_;
  #pragma unroll
  for (int n2 = 0; n2 < 8; ++n2)
    #pragma unroll
    for (int r = 0; r < 4; ++r)
      od[(size_t)r * D_ + n2 * 16 + lo] = __float2bfloat16(oacc[n2][r] * inv[r]);
}

// ---------------------------------------------------------------------------
extern "C" void kernel_launch(void* const* d_in, const int* in_sizes, int n_in,
                              void* d_out, int out_size, void* d_ws, size_t ws_size,
                              hipStream_t stream)
{
  const float* x   = (const float*)d_in[0];
  const float* l3m = (const float*)d_in[1];
  const float* wq  = (const float*)d_in[2];
  const float* wk  = (const float*)d_in[3];
  const float* wv  = (const float*)d_in[4];
  const float* wo  = (const float*)d_in[5];
  const float* rw1 = (const float*)d_in[6];
  const float* rb1 = (const float*)d_in[7];
  const float* rw2 = (const float*)d_in[8];
  const float* rb2 = (const float*)d_in[9];

  float* out = (float*)d_out;                 // [b,t,d]      4,194,304 f32
  float* kh  = out + 4194304;                 // [b,h,t,dh]   4,194,304 f32
  float* vh  = out + 8388608;                 // [b,h,t,dh]   4,194,304 f32
  float* lam = out + 12582912;                // [b,t,3]          6,144 f32

  // ws layout (80 MB):
  char* wsb = (char*)d_ws;
  float*          l2_f32 = (float*)(wsb);                        // 16 MB (local scan)
  float*          hdn    = (float*)(wsb + (16u << 20));          //  8 MB
  __hip_bfloat16* wkb    = (__hip_bfloat16*)(wsb + (24u << 20)); //  8 MB \ contiguous
  __hip_bfloat16* wvb    = (__hip_bfloat16*)(wsb + (32u << 20)); //  8 MB / [4096,2048]
  __hip_bfloat16* wob    = (__hip_bfloat16*)(wsb + (40u << 20)); //  8 MB
  __hip_bfloat16* fusedb = (__hip_bfloat16*)(wsb + (48u << 20)); //  8 MB
  __hip_bfloat16* attnb  = (__hip_bfloat16*)(wsb + (56u << 20)); //  8 MB (written step 9)
  __hip_bfloat16* khb    = (__hip_bfloat16*)(wsb + (64u << 20)); //  8 MB bf16 heads
  __hip_bfloat16* vtb    = (__hip_bfloat16*)(wsb + (72u << 20)); //  8 MB bf16 [b,h,dh,t]
  float*          carry  = (float*)attnb;   // 1 MB (64 chunks); dead before attnb written
  // d_out scratch reuse (regions written later in the stream order):
  __hip_bfloat16* wqb  = (__hip_bfloat16*)kh;                    // [16,24 MB) of d_out
  __hip_bfloat16* rw1b = (__hip_bfloat16*)kh + 4194304;          // [24,28 MB)
  __hip_bfloat16* xb   = (__hip_bfloat16*)vh;                    // [32,40 MB)
  __hip_bfloat16* qb   = (__hip_bfloat16*)out;                   // [0,8 MB); out written last

  dim3 blk(256);

  // 1. prep: x -> xb (bf16) + local EMA scan (16-chunks), x read ONCE
  prep_scan<<<dim3(2, NCH_, 2), blk, 0, stream>>>(x, xb, l2_f32);
  // 2. fp32->bf16 weights: wq, wk, wv, wo, rw1 (16B stores)
  cvt5<<<dim3(2048, 5), blk, 0, stream>>>(wq, wk, wv, wo, rw1,
                                          wqb, wkb, wvb, wob, rw1b,
                                          D_ * D_, D_ * D_, D_ * D_, D_ * D_, DR_ * D_);
  // 3. EMA pass2: cross-chunk carries (64 chunks of 16)
  ema_carry<<<dim3(64), dim3(64), 0, stream>>>(l2_f32, carry);
  // 4. qb = bf16(x @ wq^T)   (64x128 tiles -> 512 WGs)
  gemm_mfma<64, 1, false><<<dim3(16, 32), blk, 0, stream>>>(xb, wqb, nullptr, nullptr, qb, nullptr, nullptr, M_, D_, D_);
  // 5. hdn = silu(q @ rw1^T + rb1)   (64x128 -> 256 WGs)
  gemm_mfma<64, 0, true><<<dim3(8, 32), blk, 0, stream>>>(qb, rw1b, rb1, hdn, nullptr, nullptr, nullptr, M_, DR_, D_);
  // 6. lam = softmax(hdn @ rw2^T + rb2)
  router_kernel<<<dim3(512), blk, 0, stream>>>(hdn, rw2, rb2, lam);
  // 7. fused = lam0*x + lam1*l2 + lam2*l3  -> bf16 (applies EMA carry)
  fuse_bf16<<<dim3(2048), blk, 0, stream>>>(x, l2_f32, l3m, lam, carry, fusedb);
  // 8. merged KV GEMM (N=4096): kh fp32+khb bf16 heads; vh fp32+vtb bf16 transposed
  gemm_mfma<128, 4, false><<<dim3(32, 16), blk, 0, stream>>>(fusedb, wkb, nullptr, kh, khb, vh, vtb, M_, 2 * D_, D_);
  // 9. MFMA flash attention -> bf16 attnb [b,t,d]  (balanced 1-D grid)
  flash_mfma<<<dim3(512), blk, 0, stream>>>(qb, khb, vtb, attnb);
  // 10. out = attn @ wo^T   (64x128 -> 512 WGs)
  gemm_mfma<64, 0, false><<<dim3(16, 32), blk, 0, stream>>>(attnb, wob, nullptr, out, nullptr, nullptr, nullptr, M_, D_, D_);
}

// Round 5
// 343.690 us; speedup vs baseline: 1.0673x; 1.0163x over previous
//
#include <hip/hip_runtime.h>
#include <hip/hip_bf16.h>
#include <math.h>

#define B_  2
#define T_  1024
#define D_  2048
#define H_  16
#define DH_ 128
#define M_  2048          // B_*T_
#define DR_ 1024          // D_/2
#define CH_  16           // EMA chunk length
#define NCH_ 64           // chunks per sequence (T_/CH_)

typedef __attribute__((ext_vector_type(8))) short short8;
typedef __attribute__((ext_vector_type(4))) short sh4;
typedef __attribute__((ext_vector_type(4))) float f32x4;

// async global->LDS, 16B per lane, dest = wave-uniform base + lane*16
__device__ __forceinline__ void gld16(const __hip_bfloat16* g, __hip_bfloat16* l) {
  __builtin_amdgcn_global_load_lds(
      (const __attribute__((address_space(1))) unsigned int*)g,
      (__attribute__((address_space(3))) unsigned int*)l, 16, 0, 0);
}

// ---------------------------------------------------------------------------
// bf16 MFMA GEMM: C = act(A * B^T + bias). A:[M,K] bf16 rm, B:[N,K] bf16 rm.
// BM x 128 tile, BK=64 (two 32-col halves), double-buffered LDS, 2-phase
// pipeline: stage(t+1) issued BEFORE compute(t); one __syncthreads per
// K-step.  256 threads = 4 waves in 2x2.  (Known-good structure; counted
// vmcnt 4-buffer attempt regressed — needs full 8-wave template.)
// CMODE 0: C fp32 [M,N].
// CMODE 1: Cb bf16 [M,N] only.
// CMODE 4: merged KV. col<2048: C fp32 heads + Cb bf16 heads (k).
//          col>=2048: C2 fp32 heads + Cb2 bf16 transposed [b,h,dh,t] (v).
// ---------------------------------------------------------------------------
template<int BM, int CMODE, bool SILU>
__global__ __launch_bounds__(256)
void gemm_mfma(const __hip_bfloat16* __restrict__ A,
               const __hip_bfloat16* __restrict__ Bm,
               const float* __restrict__ bias,
               float* __restrict__ C, __hip_bfloat16* __restrict__ Cb,
               float* __restrict__ C2, __hip_bfloat16* __restrict__ Cb2,
               int M, int N, int K)
{
  constexpr int NI = BM / 32;           // A-fragment rows per wave (4 or 2)
  constexpr int AC = BM / 64;           // A gld16 calls per wave per half (2 or 1)
  __shared__ __hip_bfloat16 As[2][2][BM * 32];    // [buf][k-half][BM x 32]
  __shared__ __hip_bfloat16 Bs[2][2][128 * 32];
  const int tid  = threadIdx.x;
  const int wave = tid >> 6;
  const int lane = tid & 63;
  const int m0 = blockIdx.y * BM;
  const int n0 = blockIdx.x * 128;
  const int wm = (wave >> 1) * (BM / 2);   // wave's row half
  const int wn = (wave & 1) * 64;          // wave's col half

  const int srow = lane >> 2;              // 0..15 row within 16-row group
  const int scol = (lane & 3) * 8;         // bf16 element offset in k
  const __hip_bfloat16* Ag = A  + (size_t)(m0 + wave * (BM / 4) + srow) * K + scol;
  const __hip_bfloat16* Bg = Bm + (size_t)(n0 + wave * 32 + srow) * K + scol;

  const int fr = lane & 15;                // fragment row (m/n index)
  const int fk = (lane >> 4) * 8;          // fragment k offset

  f32x4 acc[NI][4];
  #pragma unroll
  for (int i = 0; i < NI; ++i)
    #pragma unroll
    for (int j = 0; j < 4; ++j) acc[i][j] = (f32x4)0.f;

  // stage one BK=64 tile (both 32-col halves) into buffer bf
  auto stage = [&](int bf, int k0) {
    #pragma unroll
    for (int h = 0; h < 2; ++h) {
      #pragma unroll
      for (int c = 0; c < AC; ++c)
        gld16(Ag + k0 + h * 32 + (size_t)(c * 16) * K,
              &As[bf][h][(wave * (BM / 4) + c * 16) * 32]);
      #pragma unroll
      for (int c = 0; c < 2; ++c)
        gld16(Bg + k0 + h * 32 + (size_t)(c * 16) * K,
              &Bs[bf][h][(wave * 32 + c * 16) * 32]);
    }
  };

  stage(0, 0);
  __syncthreads();                         // prologue drain (vmcnt(0))
  int cur = 0;
  for (int k0 = 0; k0 < K; k0 += 64) {
    if (k0 + 64 < K) stage(cur ^ 1, k0 + 64);   // issue next tile FIRST
    #pragma unroll
    for (int h = 0; h < 2; ++h) {
      short8 af[NI], bfr[4];
      #pragma unroll
      for (int i = 0; i < NI; ++i)
        af[i]  = *(const short8*)&As[cur][h][(wm + i * 16 + fr) * 32 + fk];
      #pragma unroll
      for (int j = 0; j < 4; ++j)
        bfr[j] = *(const short8*)&Bs[cur][h][(wn + j * 16 + fr) * 32 + fk];
      #pragma unroll
      for (int i = 0; i < NI; ++i)
        #pragma unroll
        for (int j = 0; j < 4; ++j)
          acc[i][j] = __builtin_amdgcn_mfma_f32_16x16x32_bf16(af[i], bfr[j], acc[i][j], 0, 0, 0);
    }
    __syncthreads();   // vmcnt(0)+lgkmcnt(0) drain: next tile landed, reads done
    cur ^= 1;
  }

  // C/D layout (m89-verified): col = lane&15, row = (lane>>4)*4 + reg
  #pragma unroll
  for (int i = 0; i < NI; ++i) {
    #pragma unroll
    for (int j = 0; j < 4; ++j) {
      const int row0 = m0 + wm + i * 16 + (lane >> 4) * 4;
      const int col  = n0 + wn + j * 16 + (lane & 15);
      float vr[4];
      #pragma unroll
      for (int r = 0; r < 4; ++r) {
        float v = acc[i][j][r];
        if (bias) v += bias[col];
        if (SILU) v = v / (1.f + __expf(-v));
        vr[r] = v;
      }
      if (CMODE == 0) {
        #pragma unroll
        for (int r = 0; r < 4; ++r) C[(size_t)(row0 + r) * N + col] = vr[r];
      } else if (CMODE == 1) {
        #pragma unroll
        for (int r = 0; r < 4; ++r) Cb[(size_t)(row0 + r) * N + col] = __float2bfloat16(vr[r]);
      } else {  // CMODE 4
        const int bb = row0 >> 10, t0v = row0 & 1023;   // row = b*T + t
        if (col < D_) {                                  // K head
          const int hh = col >> 7, dd = col & 127;
          #pragma unroll
          for (int r = 0; r < 4; ++r) {
            const size_t idx = (((size_t)(bb * H_ + hh)) * T_ + t0v + r) * DH_ + dd;
            C[idx] = vr[r];
            Cb[idx] = __float2bfloat16(vr[r]);
          }
        } else {                                         // V head (+ transposed bf16)
          const int c2 = col - D_;
          const int hh = c2 >> 7, dd = c2 & 127;
          #pragma unroll
          for (int r = 0; r < 4; ++r)
            C2[(((size_t)(bb * H_ + hh)) * T_ + t0v + r) * DH_ + dd] = vr[r];
          __hip_bfloat16 tmp[4];
          #pragma unroll
          for (int r = 0; r < 4; ++r) tmp[r] = __float2bfloat16(vr[r]);
          *(sh4*)(Cb2 + (((size_t)(bb * H_ + hh)) * DH_ + dd) * T_ + t0v) = *(const sh4*)tmp;
        }
      }
    }
  }
}

// ---------------------------------------------------------------------------
// prep_all: one launch for x-prep + 5 weight conversions.
// y==0 (x-blocks 0..255): read x once (float4), write xb (bf16, 8B store),
//   local EMA scan per 16-row chunk (fp32), and compact chunk-final lf.
// y==1..5: fp32->bf16 weight conversion (16B short8 stores).
// ---------------------------------------------------------------------------
__global__ __launch_bounds__(256)
void prep_all(const float* __restrict__ x, __hip_bfloat16* __restrict__ xb,
              float* __restrict__ l2, float* __restrict__ lf,
              const float* __restrict__ s1, const float* __restrict__ s2,
              const float* __restrict__ s3, const float* __restrict__ s4,
              const float* __restrict__ s5,
              __hip_bfloat16* d1, __hip_bfloat16* d2, __hip_bfloat16* d3,
              __hip_bfloat16* d4, __hip_bfloat16* d5,
              int n1, int n2, int n3, int n4, int n5)
{
  if (blockIdx.y == 0) {
    const int bid = blockIdx.x;
    if (bid >= 256) return;
    const int dblk = bid & 1;
    const int ch   = (bid >> 1) & 63;
    const int b    = bid >> 7;
    const int t0 = ch * CH_;
    const int d  = dblk * 1024 + threadIdx.x * 4;
    const float* xp = x  + (size_t)b * T_ * D_ + d;
    float*       lp = l2 + (size_t)b * T_ * D_ + d;
    __hip_bfloat16* xo = xb + (size_t)b * T_ * D_ + d;
    float4 s = make_float4(0.f, 0.f, 0.f, 0.f);
    #pragma unroll 4
    for (int t = t0; t < t0 + CH_; ++t) {
      float4 v = *(const float4*)(xp + (size_t)t * D_);
      __hip_bfloat16 tmp[4] = {__float2bfloat16(v.x), __float2bfloat16(v.y),
                               __float2bfloat16(v.z), __float2bfloat16(v.w)};
      *(sh4*)(xo + (size_t)t * D_) = *(const sh4*)tmp;
      s.x = 0.9f * s.x + 0.1f * v.x;
      s.y = 0.9f * s.y + 0.1f * v.y;
      s.z = 0.9f * s.z + 0.1f * v.z;
      s.w = 0.9f * s.w + 0.1f * v.w;
      *(float4*)(lp + (size_t)t * D_) = s;
    }
    // compact chunk-final for the carry scan
    *(float4*)(lf + ((size_t)b * NCH_ + ch) * D_ + d) = s;
    return;
  }
  const float* s; __hip_bfloat16* d; int n;
  switch (blockIdx.y) {
    case 1: s = s1; d = d1; n = n1; break;
    case 2: s = s2; d = d2; n = n2; break;
    case 3: s = s3; d = d3; n = n3; break;
    case 4: s = s4; d = d4; n = n4; break;
    default: s = s5; d = d5; n = n5; break;
  }
  const int i = (blockIdx.x * 256 + threadIdx.x) * 8;
  if (i < n) {
    float4 a = *(const float4*)(s + i);
    float4 b = *(const float4*)(s + i + 4);
    __hip_bfloat16 t[8] = {__float2bfloat16(a.x), __float2bfloat16(a.y),
                           __float2bfloat16(a.z), __float2bfloat16(a.w),
                           __float2bfloat16(b.x), __float2bfloat16(b.y),
                           __float2bfloat16(b.z), __float2bfloat16(b.w)};
    *(short8*)(d + i) = *(const short8*)t;
  }
}

// ---------------------------------------------------------------------------
// EMA carry via wave-parallel weighted scan.  lane = chunk (64 lanes).
// Affine composition (p,S)∘(p',S'): S = S + p*S', p = p*p' over 6
// shfl_up steps -> inclusive S_l = sum_j A^(l-j) lf_j;  carry_c = S_{c-1}.
// One wave per (b,d) chain: 4096 waves = 1024 blocks.
// ---------------------------------------------------------------------------
__global__ __launch_bounds__(256)
void ema_carry_scan(const float* __restrict__ lf, float* __restrict__ carry)
{
  const int wid  = (blockIdx.x * 256 + threadIdx.x) >> 6;   // 0..4095
  const int lane = threadIdx.x & 63;
  const int b = wid >> 11, d = wid & 2047;
  float S = lf[((size_t)b * NCH_ + lane) * D_ + d];
  float p = 0.18530201888518416f;                            // 0.9^16
  #pragma unroll
  for (int off = 1; off < 64; off <<= 1) {
    float Su = __shfl_up(S, off);
    float pu = __shfl_up(p, off);
    if (lane >= off) { S = S + p * Su; p = p * pu; }
  }
  float c = __shfl_up(S, 1);
  if (lane == 0) c = 0.f;
  carry[((size_t)b * NCH_ + lane) * D_ + d] = c;
}

// ---------------------------------------------------------------------------
// fuse_router: per block, 8 rows.
// Phase 1: lam = softmax(hdn @ rw2^T + rb2) per row (32-lane group dot +
//          shuffle reduce), written to LDS + global lam.
// Phase 2: fused = lam0*x + lam1*(l2 + 0.9^(off+1)*carry) + lam2*l3 -> bf16
//          (16B vector stores; thread covers one short8 per row).
// ---------------------------------------------------------------------------
__global__ __launch_bounds__(256)
void fuse_router(const float* __restrict__ x, const float* __restrict__ l2,
                 const float* __restrict__ l3m, const float* __restrict__ hdn,
                 const float* __restrict__ rw2, const float* __restrict__ rb2,
                 const float* __restrict__ carry, float* __restrict__ lam,
                 __hip_bfloat16* __restrict__ fb)
{
  __shared__ float lamS[8][3];
  const int tid = threadIdx.x;
  const int g = tid >> 5, l32 = tid & 31;
  const int m = blockIdx.x * 8 + g;
  const float* hp = hdn + (size_t)m * DR_;
  float s0 = 0.f, s1 = 0.f, s2 = 0.f;
  #pragma unroll
  for (int it = 0; it < 8; ++it) {
    const int k = l32 * 4 + it * 128;
    float4 h4 = *(const float4*)(hp + k);
    float4 w0 = *(const float4*)(rw2 + k);
    float4 w1 = *(const float4*)(rw2 + DR_ + k);
    float4 w2 = *(const float4*)(rw2 + 2 * DR_ + k);
    s0 += h4.x * w0.x + h4.y * w0.y + h4.z * w0.z + h4.w * w0.w;
    s1 += h4.x * w1.x + h4.y * w1.y + h4.z * w1.z + h4.w * w1.w;
    s2 += h4.x * w2.x + h4.y * w2.y + h4.z * w2.z + h4.w * w2.w;
  }
  #pragma unroll
  for (int off = 16; off > 0; off >>= 1) {
    s0 += __shfl_xor(s0, off);
    s1 += __shfl_xor(s1, off);
    s2 += __shfl_xor(s2, off);
  }
  if (l32 == 0) {
    s0 += rb2[0]; s1 += rb2[1]; s2 += rb2[2];
    float mx = fmaxf(s0, fmaxf(s1, s2));
    float e0 = __expf(s0 - mx), e1 = __expf(s1 - mx), e2 = __expf(s2 - mx);
    float inv = 1.f / (e0 + e1 + e2);
    lam[(size_t)m * 3 + 0] = e0 * inv;
    lam[(size_t)m * 3 + 1] = e1 * inv;
    lam[(size_t)m * 3 + 2] = e2 * inv;
    lamS[g][0] = e0 * inv; lamS[g][1] = e1 * inv; lamS[g][2] = e2 * inv;
  }
  __syncthreads();

  const int c = tid * 8;                    // 0..2040 (covers D_ exactly)
  #pragma unroll
  for (int r = 0; r < 8; ++r) {
    const int mm = blockIdx.x * 8 + r;
    const int bb = mm >> 10, tt = mm & 1023;
    const int ch = tt >> 4, off = tt & 15;
    const float pw = __expf((float)(off + 1) * -0.105360515657f);  // 0.9^(off+1)
    const float u0 = lamS[r][0], u1 = lamS[r][1], u2 = lamS[r][2];
    const float* xp = x   + (size_t)mm * D_ + c;
    const float* ep = l2  + (size_t)mm * D_ + c;
    const float* gp = l3m + (size_t)bb * D_ + c;
    const float* cp = carry + ((size_t)bb * NCH_ + ch) * D_ + c;
    __hip_bfloat16 tmp[8];
    #pragma unroll
    for (int q = 0; q < 2; ++q) {
      float4 xv = *(const float4*)(xp + q * 4);
      float4 ev = *(const float4*)(ep + q * 4);
      float4 gv = *(const float4*)(gp + q * 4);
      float4 cv = *(const float4*)(cp + q * 4);
      tmp[q * 4 + 0] = __float2bfloat16(u0 * xv.x + u1 * (ev.x + pw * cv.x) + u2 * gv.x);
      tmp[q * 4 + 1] = __float2bfloat16(u0 * xv.y + u1 * (ev.y + pw * cv.y) + u2 * gv.y);
      tmp[q * 4 + 2] = __float2bfloat16(u0 * xv.z + u1 * (ev.z + pw * cv.z) + u2 * gv.z);
      tmp[q * 4 + 3] = __float2bfloat16(u0 * xv.w + u1 * (ev.w + pw * cv.w) + u2 * gv.w);
    }
    *(short8*)(fb + (size_t)mm * D_ + c) = *(const short8*)tmp;
  }
}

// ---------------------------------------------------------------------------
// MFMA flash attention. 64-row Q-tile per block, 4 waves x 16 q-rows,
// 64-key K-tiles, 16x16x32 bf16 MFMA for QK^T and PV.
// DOUBLE-BUFFERED K/V LDS, ONE barrier per iteration.  Ps is wave-private
// (write rows wave*16+hi*4+r, read rows wave*16+lo: same 16-row stripe)
// so it needs no barrier.  buf[c^1] written in iter kt was last read in
// iter kt-1, separated by the end-of-(kt-1) barrier.
// LDS = 2*(64*136 + 128*72)*2B + 64*72*2B = 80,896 B -> 2 blocks/CU.
// Grid: 1-D 512 with anti-correlated qt remap (L and L+256 sum to 17
// tile-iters).  Q fragments global->reg.
// ---------------------------------------------------------------------------
__global__ __launch_bounds__(256)
void flash_mfma(const __hip_bfloat16* __restrict__ qg,
                const __hip_bfloat16* __restrict__ kg,
                const __hip_bfloat16* __restrict__ vg,
                __hip_bfloat16* __restrict__ og)
{
  __shared__ __hip_bfloat16 Ks[2][64 * 136];
  __shared__ __hip_bfloat16 Vt[2][128 * 72];
  __shared__ __hip_bfloat16 Ps[64 * 72];
  const int tid  = threadIdx.x;
  const int wave = tid >> 6, lane = tid & 63;
  const int L    = blockIdx.x;
  const int halfg = L >> 8, idx = L & 255;
  const int bh = (idx >> 4) | (halfg << 4);
  const int qt = halfg ? (15 - (idx & 15)) : (idx & 15);
  const int b = bh >> 4, h = bh & 15;
  const int q0 = qt * 64;
  const int lo = lane & 15, hi = lane >> 4;

  short8 aq[4];
  {
    const __hip_bfloat16* qsrc = qg + (size_t)(b * T_ + q0 + wave * 16 + lo) * D_ + h * DH_;
    #pragma unroll
    for (int kk = 0; kk < 4; ++kk)
      aq[kk] = *(const short8*)(qsrc + kk * 32 + hi * 8);
  }

  f32x4 oacc[8];
  #pragma unroll
  for (int i = 0; i < 8; ++i) oacc[i] = (f32x4)0.f;
  float mrow[4] = {-INFINITY, -INFINITY, -INFINITY, -INFINITY};
  float lrow[4] = {0.f, 0.f, 0.f, 0.f};

  const __hip_bfloat16* kbp = kg + (size_t)bh * T_ * DH_;
  const __hip_bfloat16* vbp = vg + (size_t)bh * DH_ * T_;
  const float scale = 0.08838834764831845f;      // 1/sqrt(128)

  short8 kreg[4], vreg[4];
  auto load_tile = [&](int k0) {
    #pragma unroll
    for (int i = 0; i < 4; ++i) {
      const int ci = tid + 256 * i;
      const int r = ci >> 4, j = ci & 15;
      kreg[i] = *(const short8*)(kbp + (size_t)(k0 + r) * DH_ + j * 8);
      const int dd = ci >> 3, j2 = ci & 7;
      vreg[i] = *(const short8*)(vbp + (size_t)dd * T_ + k0 + j2 * 8);
    }
  };
  auto write_lds = [&](int bf) {
    #pragma unroll
    for (int i = 0; i < 4; ++i) {
      const int ci = tid + 256 * i;
      const int r = ci >> 4, j = ci & 15;
      *(short8*)&Ks[bf][r * 136 + j * 8] = kreg[i];
      const int dd = ci >> 3, j2 = ci & 7;
      *(short8*)&Vt[bf][dd * 72 + j2 * 8] = vreg[i];
    }
  };

  load_tile(0);
  write_lds(0);                     // implicit vmcnt wait on tile-0 loads
  if (qt > 0) load_tile(64);        // tile 1 in flight across barrier
  __syncthreads();

  for (int kt = 0; kt <= qt; ++kt) {
    const int cur = kt & 1;
    f32x4 sc[4];
    __builtin_amdgcn_s_setprio(1);
    #pragma unroll
    for (int nt = 0; nt < 4; ++nt) {
      sc[nt] = (f32x4)0.f;
      #pragma unroll
      for (int kk = 0; kk < 4; ++kk) {
        short8 bk = *(const short8*)&Ks[cur][(nt * 16 + lo) * 136 + kk * 32 + hi * 8];
        sc[nt] = __builtin_amdgcn_mfma_f32_16x16x32_bf16(aq[kk], bk, sc[nt], 0, 0, 0);
      }
    }
    __builtin_amdgcn_s_setprio(0);
    #pragma unroll
    for (int nt = 0; nt < 4; ++nt)
      #pragma unroll
      for (int r = 0; r < 4; ++r) sc[nt][r] *= scale;
    if (kt == qt) {                           // mask only the diagonal tile
      const int qrow = q0 + wave * 16 + hi * 4;
      #pragma unroll
      for (int nt = 0; nt < 4; ++nt) {
        const int key = qt * 64 + nt * 16 + lo;
        #pragma unroll
        for (int r = 0; r < 4; ++r)
          if (key > qrow + r) sc[nt][r] = -1e30f;
      }
    }
    float alpha[4];
    #pragma unroll
    for (int r = 0; r < 4; ++r) {
      float mx = fmaxf(fmaxf(sc[0][r], sc[1][r]), fmaxf(sc[2][r], sc[3][r]));
      mx = fmaxf(mx, __shfl_xor(mx, 1));
      mx = fmaxf(mx, __shfl_xor(mx, 2));
      mx = fmaxf(mx, __shfl_xor(mx, 4));
      mx = fmaxf(mx, __shfl_xor(mx, 8));
      const float nm = fmaxf(mrow[r], mx);
      alpha[r] = __expf(mrow[r] - nm);
      mrow[r] = nm;
      float ls = 0.f;
      #pragma unroll
      for (int nt = 0; nt < 4; ++nt) {
        float p = __expf(sc[nt][r] - nm);
        sc[nt][r] = p;
        ls += p;
      }
      ls += __shfl_xor(ls, 1);
      ls += __shfl_xor(ls, 2);
      ls += __shfl_xor(ls, 4);
      ls += __shfl_xor(ls, 8);
      lrow[r] = lrow[r] * alpha[r] + ls;
    }
    #pragma unroll
    for (int nt = 0; nt < 4; ++nt)
      #pragma unroll
      for (int r = 0; r < 4; ++r)
        Ps[(wave * 16 + hi * 4 + r) * 72 + nt * 16 + lo] = __float2bfloat16(sc[nt][r]);
    #pragma unroll
    for (int n2 = 0; n2 < 8; ++n2)
      #pragma unroll
      for (int r = 0; r < 4; ++r) oacc[n2][r] *= alpha[r];
    short8 ap[2];
    #pragma unroll
    for (int k2 = 0; k2 < 2; ++k2)
      ap[k2] = *(const short8*)&Ps[(wave * 16 + lo) * 72 + k2 * 32 + hi * 8];
    __builtin_amdgcn_s_setprio(1);
    #pragma unroll
    for (int n2 = 0; n2 < 8; ++n2) {
      #pragma unroll
      for (int k2 = 0; k2 < 2; ++k2) {
        short8 bv = *(const short8*)&Vt[cur][(n2 * 16 + lo) * 72 + k2 * 32 + hi * 8];
        oacc[n2] = __builtin_amdgcn_mfma_f32_16x16x32_bf16(ap[k2], bv, oacc[n2], 0, 0, 0);
      }
    }
    __builtin_amdgcn_s_setprio(0);
    if (kt < qt) {
      write_lds(cur ^ 1);           // vmcnt waits only on tile kt+1 loads
      if (kt + 1 < qt) load_tile((kt + 2) * 64);
    }
    __syncthreads();                // single barrier per iteration
  }

  float inv[4];
  #pragma unroll
  for (int r = 0; r < 4; ++r) inv[r] = 1.f / lrow[r];
  __hip_bfloat16* od = og + (size_t)(b * T_ + q0 + wave * 16 + hi * 4) * D_ + h * DH_;
  #pragma unroll
  for (int n2 = 0; n2 < 8; ++n2)
    #pragma unroll
    for (int r = 0; r < 4; ++r)
      od[(size_t)r * D_ + n2 * 16 + lo] = __float2bfloat16(oacc[n2][r] * inv[r]);
}

// ---------------------------------------------------------------------------
extern "C" void kernel_launch(void* const* d_in, const int* in_sizes, int n_in,
                              void* d_out, int out_size, void* d_ws, size_t ws_size,
                              hipStream_t stream)
{
  const float* x   = (const float*)d_in[0];
  const float* l3m = (const float*)d_in[1];
  const float* wq  = (const float*)d_in[2];
  const float* wk  = (const float*)d_in[3];
  const float* wv  = (const float*)d_in[4];
  const float* wo  = (const float*)d_in[5];
  const float* rw1 = (const float*)d_in[6];
  const float* rb1 = (const float*)d_in[7];
  const float* rw2 = (const float*)d_in[8];
  const float* rb2 = (const float*)d_in[9];

  float* out = (float*)d_out;                 // [b,t,d]      4,194,304 f32
  float* kh  = out + 4194304;                 // [b,h,t,dh]   4,194,304 f32
  float* vh  = out + 8388608;                 // [b,h,t,dh]   4,194,304 f32
  float* lam = out + 12582912;                // [b,t,3]          6,144 f32

  // ws layout (80 MB):
  char* wsb = (char*)d_ws;
  float*          l2_f32 = (float*)(wsb);                        // 16 MB (local scan)
  float*          hdn    = (float*)(wsb + (16u << 20));          //  8 MB
  __hip_bfloat16* wkb    = (__hip_bfloat16*)(wsb + (24u << 20)); //  8 MB \ contiguous
  __hip_bfloat16* wvb    = (__hip_bfloat16*)(wsb + (32u << 20)); //  8 MB / [4096,2048]
  __hip_bfloat16* wob    = (__hip_bfloat16*)(wsb + (40u << 20)); //  8 MB
  __hip_bfloat16* fusedb = (__hip_bfloat16*)(wsb + (48u << 20)); //  8 MB
  __hip_bfloat16* attnb  = (__hip_bfloat16*)(wsb + (56u << 20)); //  8 MB (written step 7)
  __hip_bfloat16* khb    = (__hip_bfloat16*)(wsb + (64u << 20)); //  8 MB bf16 heads
  __hip_bfloat16* vtb    = (__hip_bfloat16*)(wsb + (72u << 20)); //  8 MB bf16 [b,h,dh,t]
  float*          carry  = (float*)attnb;                 // 1 MB; dead before attnb written
  float*          lf     = (float*)(wsb + (57u << 20));   // 1 MB chunk-finals (in attnb region)
  // d_out scratch reuse (regions written later in the stream order):
  __hip_bfloat16* wqb  = (__hip_bfloat16*)kh;                    // [16,24 MB) of d_out
  __hip_bfloat16* rw1b = (__hip_bfloat16*)kh + 4194304;          // [24,28 MB)
  __hip_bfloat16* xb   = (__hip_bfloat16*)vh;                    // [32,40 MB)
  __hip_bfloat16* qb   = (__hip_bfloat16*)out;                   // [0,8 MB); out written last

  dim3 blk(256);

  // 1. prep (x -> xb + EMA local scan + lf) and weight cvts, one launch
  prep_all<<<dim3(2048, 6), blk, 0, stream>>>(x, xb, l2_f32, lf,
                                              wq, wk, wv, wo, rw1,
                                              wqb, wkb, wvb, wob, rw1b,
                                              D_ * D_, D_ * D_, D_ * D_, D_ * D_, DR_ * D_);
  // 2. EMA carry: wave-parallel weighted scan over 64 chunks
  ema_carry_scan<<<dim3(1024), blk, 0, stream>>>(lf, carry);
  // 3. qb = bf16(x @ wq^T)   (64x128 tiles -> 512 WGs)
  gemm_mfma<64, 1, false><<<dim3(16, 32), blk, 0, stream>>>(xb, wqb, nullptr, nullptr, qb, nullptr, nullptr, M_, D_, D_);
  // 4. hdn = silu(q @ rw1^T + rb1)   (64x128 -> 256 WGs)
  gemm_mfma<64, 0, true><<<dim3(8, 32), blk, 0, stream>>>(qb, rw1b, rb1, hdn, nullptr, nullptr, nullptr, M_, DR_, D_);
  // 5. router + fuse in one kernel (writes lam and fusedb)
  fuse_router<<<dim3(256), blk, 0, stream>>>(x, l2_f32, l3m, hdn, rw2, rb2, carry, lam, fusedb);
  // 6. merged KV GEMM (N=4096): kh fp32+khb bf16 heads; vh fp32+vtb bf16 transposed
  gemm_mfma<128, 4, false><<<dim3(32, 16), blk, 0, stream>>>(fusedb, wkb, nullptr, kh, khb, vh, vtb, M_, 2 * D_, D_);
  // 7. MFMA flash attention -> bf16 attnb [b,t,d]  (balanced 1-D grid)
  flash_mfma<<<dim3(512), blk, 0, stream>>>(qb, khb, vtb, attnb);
  // 8. out = attn @ wo^T   (64x128 -> 512 WGs)
  gemm_mfma<64, 0, false><<<dim3(16, 32), blk, 0, stream>>>(attnb, wob, nullptr, out, nullptr, nullptr, nullptr, M_, D_, D_);
}